// Round 1
// baseline (603.067 us; speedup 1.0000x reference)
//
#include <hip/hip_runtime.h>
#include <math.h>

#define DIM_IN 128
#define DIM_H 64
#define DIM_OUT 16

// ---------- degree / dinv ----------
__global__ void k_deg(const int* __restrict__ dst, int E, float* __restrict__ deg) {
  int i = blockIdx.x * blockDim.x + threadIdx.x;
  if (i < E) atomicAdd(&deg[dst[i]], 1.0f);
}

__global__ void k_dinv(float* __restrict__ deg, int n) {
  int i = blockIdx.x * blockDim.x + threadIdx.x;
  if (i < n) deg[i] = rsqrtf(deg[i] + 1.0f);
}

// ---------- GEMM1: h = x @ W1   (N x 128) @ (128 x 64) ----------
// 64-row x 64-col tile per block, 256 threads, 4x4 register micro-tile.
// xs is XOR-swizzled (k ^= (r&3)<<2) so the 4 row-strided b128 reads are
// conflict-free while keeping total LDS at exactly 64 KiB.
__global__ __launch_bounds__(256) void k_gemm1(const float* __restrict__ x,
                                               const float* __restrict__ W,
                                               float* __restrict__ h, int n) {
  __shared__ float xs[64][128];
  __shared__ float Ws[128][64];
  const int t = threadIdx.x;
  const int base = blockIdx.x * 64;

  for (int i = t; i < 128 * 64; i += 256) Ws[i >> 6][i & 63] = W[i];
  for (int i = t; i < 64 * 128; i += 256) {
    int r = i >> 7, k = i & 127;
    float v = (base + r < n) ? x[(size_t)(base + r) * DIM_IN + k] : 0.0f;
    xs[r][k ^ ((r & 3) << 2)] = v;
  }
  __syncthreads();

  const int c0 = (t & 15) * 4;
  const int r0 = (t >> 4) * 4;
  float acc[4][4] = {};
  for (int kb = 0; kb < 128; kb += 4) {
    float xv[4][4];
    float wv[4][4];
#pragma unroll
    for (int i = 0; i < 4; ++i)
      *(float4*)xv[i] = *(const float4*)&xs[r0 + i][kb ^ (i << 2)];
#pragma unroll
    for (int kk = 0; kk < 4; ++kk)
      *(float4*)wv[kk] = *(const float4*)&Ws[kb + kk][c0];
#pragma unroll
    for (int kk = 0; kk < 4; ++kk)
#pragma unroll
      for (int i = 0; i < 4; ++i)
#pragma unroll
        for (int j = 0; j < 4; ++j)
          acc[i][j] = fmaf(xv[i][kk], wv[kk][j], acc[i][j]);
  }

#pragma unroll
  for (int i = 0; i < 4; ++i) {
    int r = base + r0 + i;
    if (r < n)
      *(float4*)&h[(size_t)r * DIM_H + c0] =
          make_float4(acc[i][0], acc[i][1], acc[i][2], acc[i][3]);
  }
}

// ---------- GEMM2: h2 = relu(agg1) @ W2   (N x 64) @ (64 x 16) ----------
// one thread per row, W2 staged in LDS (broadcast reads).
__global__ __launch_bounds__(256) void k_gemm2(const float* __restrict__ a,
                                               const float* __restrict__ W,
                                               float* __restrict__ h2, int n) {
  __shared__ float Ws[64][16];
  const int t = threadIdx.x;
  for (int i = t; i < 64 * 16; i += 256) Ws[i >> 4][i & 15] = W[i];
  __syncthreads();
  int r = blockIdx.x * 256 + t;
  if (r >= n) return;
  const float4* ap = (const float4*)(a + (size_t)r * DIM_H);
  float acc[16] = {};
  for (int k4 = 0; k4 < 16; ++k4) {
    float4 v = ap[k4];
    float vv[4] = {fmaxf(v.x, 0.f), fmaxf(v.y, 0.f), fmaxf(v.z, 0.f),
                   fmaxf(v.w, 0.f)};
#pragma unroll
    for (int kk = 0; kk < 4; ++kk) {
      int k = k4 * 4 + kk;
#pragma unroll
      for (int j = 0; j < 16; ++j) acc[j] = fmaf(vv[kk], Ws[k][j], acc[j]);
    }
  }
  float4* hp = (float4*)(h2 + (size_t)r * DIM_OUT);
  hp[0] = make_float4(acc[0], acc[1], acc[2], acc[3]);
  hp[1] = make_float4(acc[4], acc[5], acc[6], acc[7]);
  hp[2] = make_float4(acc[8], acc[9], acc[10], acc[11]);
  hp[3] = make_float4(acc[12], acc[13], acc[14], acc[15]);
}

// ---------- self-loop + bias init: agg = h * dinv^2 + b ----------
template <int D4>  // D4 = (row dim)/4
__global__ void k_self(const float* __restrict__ h, const float* __restrict__ dinv,
                       const float* __restrict__ b, float* __restrict__ agg, int n) {
  int i = blockIdx.x * blockDim.x + threadIdx.x;  // float4 index
  if (i >= n * D4) return;
  int r = i / D4;
  int c4 = i - r * D4;
  float s = dinv[r];
  s *= s;
  float4 hv = ((const float4*)h)[i];
  float4 bv = ((const float4*)b)[c4];
  ((float4*)agg)[i] = make_float4(fmaf(hv.x, s, bv.x), fmaf(hv.y, s, bv.y),
                                  fmaf(hv.z, s, bv.z), fmaf(hv.w, s, bv.w));
}

// ---------- edge scatter: agg[dst] += h[src] * dinv[src]*dinv[dst] ----------
__global__ void k_scatter64(const float* __restrict__ h, const int* __restrict__ src,
                            const int* __restrict__ dst, const float* __restrict__ dinv,
                            float* __restrict__ agg, int E) {
  unsigned tid = blockIdx.x * blockDim.x + threadIdx.x;
  int e = tid >> 6;
  int c = tid & 63;
  if (e >= E) return;
  int s = src[e], d = dst[e];
  float w = dinv[s] * dinv[d];
  atomicAdd(&agg[(size_t)d * DIM_H + c], h[(size_t)s * DIM_H + c] * w);
}

__global__ void k_scatter16(const float* __restrict__ h, const int* __restrict__ src,
                            const int* __restrict__ dst, const float* __restrict__ dinv,
                            float* __restrict__ agg, int E) {
  unsigned tid = blockIdx.x * blockDim.x + threadIdx.x;
  int e = tid >> 4;
  int c = tid & 15;
  if (e >= E) return;
  int s = src[e], d = dst[e];
  float w = dinv[s] * dinv[d];
  atomicAdd(&agg[(size_t)d * DIM_OUT + c], h[(size_t)s * DIM_OUT + c] * w);
}

// ---------- row-wise log_softmax over 16 columns (in place) ----------
__global__ void k_lsm(float* __restrict__ out, int n) {
  int r = blockIdx.x * blockDim.x + threadIdx.x;
  if (r >= n) return;
  float4* p = (float4*)(out + (size_t)r * DIM_OUT);
  float4 q0 = p[0], q1 = p[1], q2 = p[2], q3 = p[3];
  float v[16] = {q0.x, q0.y, q0.z, q0.w, q1.x, q1.y, q1.z, q1.w,
                 q2.x, q2.y, q2.z, q2.w, q3.x, q3.y, q3.z, q3.w};
  float m = v[0];
#pragma unroll
  for (int j = 1; j < 16; ++j) m = fmaxf(m, v[j]);
  float ssum = 0.f;
#pragma unroll
  for (int j = 0; j < 16; ++j) ssum += expf(v[j] - m);
  float l = m + logf(ssum);
  p[0] = make_float4(v[0] - l, v[1] - l, v[2] - l, v[3] - l);
  p[1] = make_float4(v[4] - l, v[5] - l, v[6] - l, v[7] - l);
  p[2] = make_float4(v[8] - l, v[9] - l, v[10] - l, v[11] - l);
  p[3] = make_float4(v[12] - l, v[13] - l, v[14] - l, v[15] - l);
}

extern "C" void kernel_launch(void* const* d_in, const int* in_sizes, int n_in,
                              void* d_out, int out_size, void* d_ws, size_t ws_size,
                              hipStream_t stream) {
  const float* x  = (const float*)d_in[0];
  const int*   ei = (const int*)d_in[1];   // edge_index [2, E] (int32 per harness)
  const float* W1 = (const float*)d_in[2];
  const float* b1 = (const float*)d_in[3];
  const float* W2 = (const float*)d_in[4];
  const float* b2 = (const float*)d_in[5];
  float* out = (float*)d_out;

  const int n = in_sizes[0] / DIM_IN;  // 100000
  const int E = in_sizes[1] / 2;       // 1600000
  const int* srcv = ei;
  const int* dstv = ei + E;

  float* ws   = (float*)d_ws;
  float* dinv = ws;                          // n (deg -> dinv in place)
  float* h1   = dinv + n;                    // n*64
  float* agg1 = h1 + (size_t)n * DIM_H;      // n*64
  float* h2   = agg1 + (size_t)n * DIM_H;    // n*16

  hipMemsetAsync(dinv, 0, (size_t)n * sizeof(float), stream);
  k_deg<<<(E + 255) / 256, 256, 0, stream>>>(dstv, E, dinv);
  k_dinv<<<(n + 255) / 256, 256, 0, stream>>>(dinv, n);

  // layer 1
  k_gemm1<<<(n + 63) / 64, 256, 0, stream>>>(x, W1, h1, n);
  k_self<16><<<((n * 16) + 255) / 256, 256, 0, stream>>>(h1, dinv, b1, agg1, n);
  {
    long long tt = (long long)E * 64;
    k_scatter64<<<(unsigned)((tt + 255) / 256), 256, 0, stream>>>(h1, srcv, dstv,
                                                                  dinv, agg1, E);
  }

  // layer 2 (relu fused into GEMM2 read)
  k_gemm2<<<(n + 255) / 256, 256, 0, stream>>>(agg1, W2, h2, n);
  k_self<4><<<((n * 4) + 255) / 256, 256, 0, stream>>>(h2, dinv, b2, out, n);
  {
    long long tt = (long long)E * 16;
    k_scatter16<<<(unsigned)((tt + 255) / 256), 256, 0, stream>>>(h2, srcv, dstv,
                                                                  dinv, out, E);
  }

  k_lsm<<<(n + 255) / 256, 256, 0, stream>>>(out, n);
}

// Round 2
// 426.826 us; speedup vs baseline: 1.4129x; 1.4129x over previous
//
#include <hip/hip_runtime.h>
#include <math.h>

#define DIM_IN 128
#define DIM_H 64
#define DIM_OUT 16

// ======================= CSR build =======================

__global__ void k_degi(const int* __restrict__ dst, int E, int* __restrict__ deg) {
  int i = blockIdx.x * blockDim.x + threadIdx.x;
  if (i < E) atomicAdd(&deg[dst[i]], 1);
}

__global__ void k_dinv(const int* __restrict__ deg, float* __restrict__ dinv, int n) {
  int i = blockIdx.x * blockDim.x + threadIdx.x;
  if (i < n) dinv[i] = rsqrtf((float)deg[i] + 1.0f);
}

// per-block sums of deg
__global__ __launch_bounds__(256) void k_blocksum(const int* __restrict__ deg, int n,
                                                  int* __restrict__ bsum) {
  __shared__ int sd[256];
  int t = threadIdx.x;
  int i = blockIdx.x * 256 + t;
  sd[t] = (i < n) ? deg[i] : 0;
  __syncthreads();
  for (int s = 128; s > 0; s >>= 1) {
    if (t < s) sd[t] += sd[t + s];
    __syncthreads();
  }
  if (t == 0) bsum[blockIdx.x] = sd[0];
}

// single-block exclusive scan of bsum[nb], nb <= 512
__global__ __launch_bounds__(512) void k_scanb(int* __restrict__ bsum, int nb) {
  __shared__ int sb[512];
  int t = threadIdx.x;
  int v = (t < nb) ? bsum[t] : 0;
  sb[t] = v;
  __syncthreads();
  for (int off = 1; off < 512; off <<= 1) {
    int add = (t >= off) ? sb[t - off] : 0;
    __syncthreads();
    sb[t] += add;
    __syncthreads();
  }
  if (t < nb) bsum[t] = sb[t] - v;  // exclusive
}

// rowptr[i] = exclusive_scan(deg)[i]; cursor = copy
__global__ __launch_bounds__(256) void k_rowptr(const int* __restrict__ deg,
                                                const int* __restrict__ bsum, int n,
                                                int* __restrict__ rowptr,
                                                int* __restrict__ cursor) {
  __shared__ int sd[256];
  int t = threadIdx.x;
  int i = blockIdx.x * 256 + t;
  int v = (i < n) ? deg[i] : 0;
  sd[t] = v;
  __syncthreads();
  for (int off = 1; off < 256; off <<= 1) {
    int add = (t >= off) ? sd[t - off] : 0;
    __syncthreads();
    sd[t] += add;
    __syncthreads();
  }
  if (i < n) {
    int e = sd[t] - v + bsum[blockIdx.x];
    rowptr[i] = e;
    cursor[i] = e;
  }
}

__global__ void k_fillcsr(const int* __restrict__ src, const int* __restrict__ dst,
                          int E, int* __restrict__ cursor, int* __restrict__ srcs) {
  int e = blockIdx.x * blockDim.x + threadIdx.x;
  if (e < E) {
    int d = dst[e];
    int pos = atomicAdd(&cursor[d], 1);
    srcs[pos] = src[e];
  }
}

// ======================= GEMMs =======================

// h = x @ W1   (N x 128) @ (128 x 64), 64x64 tile, 4x4 micro-tile
__global__ __launch_bounds__(256) void k_gemm1(const float* __restrict__ x,
                                               const float* __restrict__ W,
                                               float* __restrict__ h, int n) {
  __shared__ float xs[64][128];
  __shared__ float Ws[128][64];
  const int t = threadIdx.x;
  const int base = blockIdx.x * 64;

  for (int i = t; i < 128 * 64; i += 256) Ws[i >> 6][i & 63] = W[i];
  for (int i = t; i < 64 * 128; i += 256) {
    int r = i >> 7, k = i & 127;
    float v = (base + r < n) ? x[(size_t)(base + r) * DIM_IN + k] : 0.0f;
    xs[r][k ^ ((r & 3) << 2)] = v;
  }
  __syncthreads();

  const int c0 = (t & 15) * 4;
  const int r0 = (t >> 4) * 4;
  float acc[4][4] = {};
  for (int kb = 0; kb < 128; kb += 4) {
    float xv[4][4];
    float wv[4][4];
#pragma unroll
    for (int i = 0; i < 4; ++i)
      *(float4*)xv[i] = *(const float4*)&xs[r0 + i][kb ^ (i << 2)];
#pragma unroll
    for (int kk = 0; kk < 4; ++kk)
      *(float4*)wv[kk] = *(const float4*)&Ws[kb + kk][c0];
#pragma unroll
    for (int kk = 0; kk < 4; ++kk)
#pragma unroll
      for (int i = 0; i < 4; ++i)
#pragma unroll
        for (int j = 0; j < 4; ++j)
          acc[i][j] = fmaf(xv[i][kk], wv[kk][j], acc[i][j]);
  }

#pragma unroll
  for (int i = 0; i < 4; ++i) {
    int r = base + r0 + i;
    if (r < n)
      *(float4*)&h[(size_t)r * DIM_H + c0] =
          make_float4(acc[i][0], acc[i][1], acc[i][2], acc[i][3]);
  }
}

// h2 = relu(a) @ W2   (N x 64) @ (64 x 16), one thread per row
__global__ __launch_bounds__(256) void k_gemm2(const float* __restrict__ a,
                                               const float* __restrict__ W,
                                               float* __restrict__ h2, int n) {
  __shared__ float Ws[64][16];
  const int t = threadIdx.x;
  for (int i = t; i < 64 * 16; i += 256) Ws[i >> 4][i & 15] = W[i];
  __syncthreads();
  int r = blockIdx.x * 256 + t;
  if (r >= n) return;
  const float4* ap = (const float4*)(a + (size_t)r * DIM_H);
  float acc[16] = {};
  for (int k4 = 0; k4 < 16; ++k4) {
    float4 v = ap[k4];
    float vv[4] = {fmaxf(v.x, 0.f), fmaxf(v.y, 0.f), fmaxf(v.z, 0.f),
                   fmaxf(v.w, 0.f)};
#pragma unroll
    for (int kk = 0; kk < 4; ++kk) {
      int k = k4 * 4 + kk;
#pragma unroll
      for (int j = 0; j < 16; ++j) acc[j] = fmaf(vv[kk], Ws[k][j], acc[j]);
    }
  }
  float4* hp = (float4*)(h2 + (size_t)r * DIM_OUT);
  hp[0] = make_float4(acc[0], acc[1], acc[2], acc[3]);
  hp[1] = make_float4(acc[4], acc[5], acc[6], acc[7]);
  hp[2] = make_float4(acc[8], acc[9], acc[10], acc[11]);
  hp[3] = make_float4(acc[12], acc[13], acc[14], acc[15]);
}

// ======================= gather aggregation =======================

// layer 1: one 64-lane wave per node; lane = column.
// agg[d][lane] = sum_{s in N(d)} h[s][lane]*dinv[s]*dinv[d] + h[d][lane]*dinv[d]^2 + b[lane]
__global__ __launch_bounds__(256) void k_gather64(const float* __restrict__ h,
                                                  const int* __restrict__ srcs,
                                                  const int* __restrict__ rowptr,
                                                  const int* __restrict__ deg,
                                                  const float* __restrict__ dinv,
                                                  const float* __restrict__ b,
                                                  float* __restrict__ out, int n) {
  int node = blockIdx.x * 4 + (threadIdx.x >> 6);
  int lane = threadIdx.x & 63;
  if (node >= n) return;
  int start = rowptr[node];
  int cnt = deg[node];
  float dd = dinv[node];
  float acc = h[(size_t)node * DIM_H + lane] * dd * dd + b[lane];
  for (int j0 = 0; j0 < cnt; j0 += 64) {
    int rem = cnt - j0;
    if (rem > 64) rem = 64;
    int s_l = (lane < rem) ? srcs[start + j0 + lane] : 0;
    float w_l = dinv[s_l] * dd;
    for (int j = 0; j < rem; ++j) {
      int s = __shfl(s_l, j);
      float w = __shfl(w_l, j);
      acc += h[(size_t)s * DIM_H + lane] * w;
    }
  }
  out[(size_t)node * DIM_H + lane] = acc;
}

// layer 2: 16-lane group per node; fused self-loop + bias + log_softmax.
__global__ __launch_bounds__(256) void k_gather16(const float* __restrict__ h,
                                                  const int* __restrict__ srcs,
                                                  const int* __restrict__ rowptr,
                                                  const int* __restrict__ deg,
                                                  const float* __restrict__ dinv,
                                                  const float* __restrict__ b,
                                                  float* __restrict__ out, int n) {
  int node = blockIdx.x * 16 + (threadIdx.x >> 4);
  int lane = threadIdx.x & 15;
  int gbase = (threadIdx.x & 63) & 48;  // group base lane within wave
  if (node >= n) return;
  int start = rowptr[node];
  int cnt = deg[node];
  float dd = dinv[node];
  float acc = h[(size_t)node * DIM_OUT + lane] * dd * dd + b[lane];
  for (int j0 = 0; j0 < cnt; j0 += 16) {
    int rem = cnt - j0;
    if (rem > 16) rem = 16;
    int s_l = (lane < rem) ? srcs[start + j0 + lane] : 0;
    float w_l = dinv[s_l] * dd;
    for (int j = 0; j < rem; ++j) {
      int s = __shfl(s_l, gbase + j);
      float w = __shfl(w_l, gbase + j);
      acc += h[(size_t)s * DIM_OUT + lane] * w;
    }
  }
  // log_softmax across the 16 lanes of this group
  float m = acc;
#pragma unroll
  for (int off = 1; off < 16; off <<= 1) m = fmaxf(m, __shfl_xor(m, off));
  float e = expf(acc - m);
  float ssum = e;
#pragma unroll
  for (int off = 1; off < 16; off <<= 1) ssum += __shfl_xor(ssum, off);
  out[(size_t)node * DIM_OUT + lane] = acc - m - logf(ssum);
}

// ======================= launch =======================

extern "C" void kernel_launch(void* const* d_in, const int* in_sizes, int n_in,
                              void* d_out, int out_size, void* d_ws, size_t ws_size,
                              hipStream_t stream) {
  const float* x  = (const float*)d_in[0];
  const int*   ei = (const int*)d_in[1];
  const float* W1 = (const float*)d_in[2];
  const float* b1 = (const float*)d_in[3];
  const float* W2 = (const float*)d_in[4];
  const float* b2 = (const float*)d_in[5];
  float* out = (float*)d_out;

  const int n = in_sizes[0] / DIM_IN;  // 100000
  const int E = in_sizes[1] / 2;       // 1600000
  const int* srcv = ei;
  const int* dstv = ei + E;

  char* wsb = (char*)d_ws;
  int* degi   = (int*)wsb;                        wsb += (size_t)n * 4;
  int* rowptr = (int*)wsb;                        wsb += (size_t)n * 4;
  int* cursor = (int*)wsb;                        wsb += (size_t)n * 4;
  int* bsum   = (int*)wsb;                        wsb += 512 * 4;
  int* srcs   = (int*)wsb;                        wsb += (size_t)E * 4;
  float* dinv = (float*)wsb;                      wsb += (size_t)n * 4;
  float* h1   = (float*)wsb;                      wsb += (size_t)n * DIM_H * 4;
  float* agg1 = (float*)wsb;                      wsb += (size_t)n * DIM_H * 4;
  float* h2   = (float*)wsb;                      wsb += (size_t)n * DIM_OUT * 4;

  const int nb = (n + 255) / 256;  // 391 <= 512

  // CSR build
  hipMemsetAsync(degi, 0, (size_t)n * 4, stream);
  k_degi<<<(E + 255) / 256, 256, 0, stream>>>(dstv, E, degi);
  k_dinv<<<(n + 255) / 256, 256, 0, stream>>>(degi, dinv, n);
  k_blocksum<<<nb, 256, 0, stream>>>(degi, n, bsum);
  k_scanb<<<1, 512, 0, stream>>>(bsum, nb);
  k_rowptr<<<nb, 256, 0, stream>>>(degi, bsum, n, rowptr, cursor);
  k_fillcsr<<<(E + 255) / 256, 256, 0, stream>>>(srcv, dstv, E, cursor, srcs);

  // layer 1
  k_gemm1<<<(n + 63) / 64, 256, 0, stream>>>(x, W1, h1, n);
  k_gather64<<<(n + 3) / 4, 256, 0, stream>>>(h1, srcs, rowptr, degi, dinv, b1,
                                              agg1, n);

  // layer 2 (relu fused into GEMM2 read; self+bias+log_softmax fused into gather)
  k_gemm2<<<(n + 255) / 256, 256, 0, stream>>>(agg1, W2, h2, n);
  k_gather16<<<(n + 15) / 16, 256, 0, stream>>>(h2, srcs, rowptr, degi, dinv, b2,
                                                out, n);
}

// Round 3
// 319.197 us; speedup vs baseline: 1.8893x; 1.3372x over previous
//
#include <hip/hip_runtime.h>
#include <math.h>

#define DIM_IN 128
#define DIM_H 64
#define DIM_OUT 16
#define NBSHIFT 8  // 256 nodes per bucket

// ======================= bucket histogram =======================
__global__ __launch_bounds__(256) void k_bhist(const int* __restrict__ dst, int E,
                                               int NB, int* __restrict__ gbhist) {
  __shared__ int lh[512];
  int t = threadIdx.x;
  lh[t] = 0;
  lh[t + 256] = 0;
  __syncthreads();
  for (int i = blockIdx.x * 256 + t; i < E; i += gridDim.x * 256)
    atomicAdd(&lh[dst[i] >> NBSHIFT], 1);
  __syncthreads();
  for (int b = t; b < NB; b += 256) {
    int c = lh[b];
    if (c) atomicAdd(&gbhist[b], c);
  }
}

// exclusive scan of gbhist[NB] -> bbase, bcursor (NB <= 512), single block
__global__ __launch_bounds__(512) void k_bscan(const int* __restrict__ gbhist, int NB,
                                               int* __restrict__ bbase,
                                               int* __restrict__ bcursor) {
  __shared__ int sb[512];
  int t = threadIdx.x;
  int v = (t < NB) ? gbhist[t] : 0;
  sb[t] = v;
  __syncthreads();
  for (int off = 1; off < 512; off <<= 1) {
    int add = (t >= off) ? sb[t - off] : 0;
    __syncthreads();
    sb[t] += add;
    __syncthreads();
  }
  if (t < NB) {
    int e = sb[t] - v;
    bbase[t] = e;
    bcursor[t] = e;
  }
}

// ======================= partition into bucket regions =======================
// each block handles a 16384-edge chunk; per-bucket LDS count -> one global
// atomic reservation per bucket -> coalesced-ish chunk writes of (src,dst).
__global__ __launch_bounds__(256) void k_part(const int* __restrict__ src,
                                              const int* __restrict__ dst, int E,
                                              int NB, int* __restrict__ bcursor,
                                              int2* __restrict__ pairs) {
  __shared__ int lh[512];
  __shared__ int lcur[512];
  int t = threadIdx.x;
  lh[t] = 0;
  lh[t + 256] = 0;
  __syncthreads();
  int e0 = blockIdx.x * 16384;
  int e1 = min(E, e0 + 16384);
  for (int i = e0 + t; i < e1; i += 256) atomicAdd(&lh[dst[i] >> NBSHIFT], 1);
  __syncthreads();
  for (int b = t; b < NB; b += 256) {
    int c = lh[b];
    lcur[b] = c ? atomicAdd(&bcursor[b], c) : 0;
  }
  __syncthreads();
  for (int i = e0 + t; i < e1; i += 256) {
    int d = dst[i];
    int pos = atomicAdd(&lcur[d >> NBSHIFT], 1);
    pairs[pos] = make_int2(src[i], d);
  }
}

// ======================= per-bucket CSR + deg + dinv =======================
// one block per bucket: node histogram + scan in LDS, then in-bucket scatter.
__global__ __launch_bounds__(256) void k_csr(const int2* __restrict__ pairs,
                                             const int* __restrict__ gbhist,
                                             const int* __restrict__ bbase, int n,
                                             int* __restrict__ degi,
                                             float* __restrict__ dinv,
                                             int* __restrict__ rowptr,
                                             int* __restrict__ srcs) {
  __shared__ int nh[256];
  __shared__ int ncur[256];
  int t = threadIdx.x;
  int b = blockIdx.x;
  int base = bbase[b];
  int cnt = gbhist[b];
  nh[t] = 0;
  __syncthreads();
  for (int i = t; i < cnt; i += 256) atomicAdd(&nh[pairs[base + i].y & 255], 1);
  __syncthreads();
  int node = (b << NBSHIFT) + t;
  int v = nh[t];
  if (node < n) {
    degi[node] = v;
    dinv[node] = rsqrtf((float)v + 1.0f);
  }
  // exclusive scan of nh
  __syncthreads();
  for (int off = 1; off < 256; off <<= 1) {
    int add = (t >= off) ? nh[t - off] : 0;
    __syncthreads();
    nh[t] += add;
    __syncthreads();
  }
  int excl = nh[t] - v;
  if (node < n) rowptr[node] = base + excl;
  ncur[t] = base + excl;
  __syncthreads();
  for (int i = t; i < cnt; i += 256) {
    int2 p = pairs[base + i];
    int pos = atomicAdd(&ncur[p.y & 255], 1);
    srcs[pos] = p.x;
  }
}

// ======================= GEMMs =======================

__global__ __launch_bounds__(256) void k_gemm1(const float* __restrict__ x,
                                               const float* __restrict__ W,
                                               float* __restrict__ h, int n) {
  __shared__ float xs[64][128];
  __shared__ float Ws[128][64];
  const int t = threadIdx.x;
  const int base = blockIdx.x * 64;

  for (int i = t; i < 128 * 64; i += 256) Ws[i >> 6][i & 63] = W[i];
  for (int i = t; i < 64 * 128; i += 256) {
    int r = i >> 7, k = i & 127;
    float v = (base + r < n) ? x[(size_t)(base + r) * DIM_IN + k] : 0.0f;
    xs[r][k ^ ((r & 3) << 2)] = v;
  }
  __syncthreads();

  const int c0 = (t & 15) * 4;
  const int r0 = (t >> 4) * 4;
  float acc[4][4] = {};
  for (int kb = 0; kb < 128; kb += 4) {
    float xv[4][4];
    float wv[4][4];
#pragma unroll
    for (int i = 0; i < 4; ++i)
      *(float4*)xv[i] = *(const float4*)&xs[r0 + i][kb ^ (i << 2)];
#pragma unroll
    for (int kk = 0; kk < 4; ++kk)
      *(float4*)wv[kk] = *(const float4*)&Ws[kb + kk][c0];
#pragma unroll
    for (int kk = 0; kk < 4; ++kk)
#pragma unroll
      for (int i = 0; i < 4; ++i)
#pragma unroll
        for (int j = 0; j < 4; ++j)
          acc[i][j] = fmaf(xv[i][kk], wv[kk][j], acc[i][j]);
  }

#pragma unroll
  for (int i = 0; i < 4; ++i) {
    int r = base + r0 + i;
    if (r < n)
      *(float4*)&h[(size_t)r * DIM_H + c0] =
          make_float4(acc[i][0], acc[i][1], acc[i][2], acc[i][3]);
  }
}

__global__ __launch_bounds__(256) void k_gemm2(const float* __restrict__ a,
                                               const float* __restrict__ W,
                                               float* __restrict__ h2, int n) {
  __shared__ float Ws[64][16];
  const int t = threadIdx.x;
  for (int i = t; i < 64 * 16; i += 256) Ws[i >> 4][i & 15] = W[i];
  __syncthreads();
  int r = blockIdx.x * 256 + t;
  if (r >= n) return;
  const float4* ap = (const float4*)(a + (size_t)r * DIM_H);
  float acc[16] = {};
  for (int k4 = 0; k4 < 16; ++k4) {
    float4 v = ap[k4];
    float vv[4] = {fmaxf(v.x, 0.f), fmaxf(v.y, 0.f), fmaxf(v.z, 0.f),
                   fmaxf(v.w, 0.f)};
#pragma unroll
    for (int kk = 0; kk < 4; ++kk) {
      int k = k4 * 4 + kk;
#pragma unroll
      for (int j = 0; j < 16; ++j) acc[j] = fmaf(vv[kk], Ws[k][j], acc[j]);
    }
  }
  float4* hp = (float4*)(h2 + (size_t)r * DIM_OUT);
  hp[0] = make_float4(acc[0], acc[1], acc[2], acc[3]);
  hp[1] = make_float4(acc[4], acc[5], acc[6], acc[7]);
  hp[2] = make_float4(acc[8], acc[9], acc[10], acc[11]);
  hp[3] = make_float4(acc[12], acc[13], acc[14], acc[15]);
}

// ======================= gather aggregation =======================

__global__ __launch_bounds__(256) void k_gather64(const float* __restrict__ h,
                                                  const int* __restrict__ srcs,
                                                  const int* __restrict__ rowptr,
                                                  const int* __restrict__ deg,
                                                  const float* __restrict__ dinv,
                                                  const float* __restrict__ b,
                                                  float* __restrict__ out, int n) {
  int node = blockIdx.x * 4 + (threadIdx.x >> 6);
  int lane = threadIdx.x & 63;
  if (node >= n) return;
  int start = rowptr[node];
  int cnt = deg[node];
  float dd = dinv[node];
  float acc = h[(size_t)node * DIM_H + lane] * dd * dd + b[lane];
  for (int j0 = 0; j0 < cnt; j0 += 64) {
    int rem = cnt - j0;
    if (rem > 64) rem = 64;
    int s_l = (lane < rem) ? srcs[start + j0 + lane] : 0;
    float w_l = dinv[s_l] * dd;
    for (int j = 0; j < rem; ++j) {
      int s = __shfl(s_l, j);
      float w = __shfl(w_l, j);
      acc += h[(size_t)s * DIM_H + lane] * w;
    }
  }
  out[(size_t)node * DIM_H + lane] = acc;
}

__global__ __launch_bounds__(256) void k_gather16(const float* __restrict__ h,
                                                  const int* __restrict__ srcs,
                                                  const int* __restrict__ rowptr,
                                                  const int* __restrict__ deg,
                                                  const float* __restrict__ dinv,
                                                  const float* __restrict__ b,
                                                  float* __restrict__ out, int n) {
  int node = blockIdx.x * 16 + (threadIdx.x >> 4);
  int lane = threadIdx.x & 15;
  int gbase = (threadIdx.x & 63) & 48;
  if (node >= n) return;
  int start = rowptr[node];
  int cnt = deg[node];
  float dd = dinv[node];
  float acc = h[(size_t)node * DIM_OUT + lane] * dd * dd + b[lane];
  for (int j0 = 0; j0 < cnt; j0 += 16) {
    int rem = cnt - j0;
    if (rem > 16) rem = 16;
    int s_l = (lane < rem) ? srcs[start + j0 + lane] : 0;
    float w_l = dinv[s_l] * dd;
    for (int j = 0; j < rem; ++j) {
      int s = __shfl(s_l, gbase + j);
      float w = __shfl(w_l, gbase + j);
      acc += h[(size_t)s * DIM_OUT + lane] * w;
    }
  }
  float m = acc;
#pragma unroll
  for (int off = 1; off < 16; off <<= 1) m = fmaxf(m, __shfl_xor(m, off));
  float e = expf(acc - m);
  float ssum = e;
#pragma unroll
  for (int off = 1; off < 16; off <<= 1) ssum += __shfl_xor(ssum, off);
  out[(size_t)node * DIM_OUT + lane] = acc - m - logf(ssum);
}

// ======================= launch =======================

extern "C" void kernel_launch(void* const* d_in, const int* in_sizes, int n_in,
                              void* d_out, int out_size, void* d_ws, size_t ws_size,
                              hipStream_t stream) {
  const float* x  = (const float*)d_in[0];
  const int*   ei = (const int*)d_in[1];
  const float* W1 = (const float*)d_in[2];
  const float* b1 = (const float*)d_in[3];
  const float* W2 = (const float*)d_in[4];
  const float* b2 = (const float*)d_in[5];
  float* out = (float*)d_out;

  const int n = in_sizes[0] / DIM_IN;  // 100000
  const int E = in_sizes[1] / 2;       // 1600000
  const int* srcv = ei;
  const int* dstv = ei + E;
  const int NB = (n + 255) >> NBSHIFT;  // 391

  char* wsb = (char*)d_ws;
  int* degi    = (int*)wsb;   wsb += (size_t)n * 4;
  int* rowptr  = (int*)wsb;   wsb += (size_t)n * 4;
  float* dinv  = (float*)wsb; wsb += (size_t)n * 4;
  int* gbhist  = (int*)wsb;   wsb += 512 * 4;
  int* bbase   = (int*)wsb;   wsb += 512 * 4;
  int* bcursor = (int*)wsb;   wsb += 512 * 4;
  int* srcs    = (int*)wsb;   wsb += (size_t)E * 4;
  float* h1    = (float*)wsb; wsb += (size_t)n * DIM_H * 4;
  float* agg1  = (float*)wsb; wsb += (size_t)n * DIM_H * 4;
  float* h2    = (float*)wsb; wsb += (size_t)n * DIM_OUT * 4;
  // pairs (E int2 = 12.8 MB) aliases agg1 (25.6 MB): dead before k_gather64 writes
  int2* pairs = (int2*)agg1;

  // ---- CSR build (counting sort, no random-4B-scatter writes) ----
  hipMemsetAsync(gbhist, 0, 512 * 4, stream);
  k_bhist<<<128, 256, 0, stream>>>(dstv, E, NB, gbhist);
  k_bscan<<<1, 512, 0, stream>>>(gbhist, NB, bbase, bcursor);
  k_part<<<(E + 16383) / 16384, 256, 0, stream>>>(srcv, dstv, E, NB, bcursor, pairs);
  k_csr<<<NB, 256, 0, stream>>>(pairs, gbhist, bbase, n, degi, dinv, rowptr, srcs);

  // ---- layer 1 ----
  k_gemm1<<<(n + 63) / 64, 256, 0, stream>>>(x, W1, h1, n);
  k_gather64<<<(n + 3) / 4, 256, 0, stream>>>(h1, srcs, rowptr, degi, dinv, b1,
                                              agg1, n);

  // ---- layer 2 ----
  k_gemm2<<<(n + 255) / 256, 256, 0, stream>>>(agg1, W2, h2, n);
  k_gather16<<<(n + 15) / 16, 256, 0, stream>>>(h2, srcs, rowptr, degi, dinv, b2,
                                                out, n);
}

// Round 4
// 224.267 us; speedup vs baseline: 2.6891x; 1.4233x over previous
//
#include <hip/hip_runtime.h>
#include <math.h>

#define DIM_IN 128
#define DIM_H 64
#define DIM_OUT 16
#define NBSHIFT 8  // 256 nodes per bucket

__device__ __forceinline__ ushort f2bf(float f) {
  uint u = __float_as_uint(f);
  return (ushort)((u + 0x7FFF + ((u >> 16) & 1)) >> 16);
}
__device__ __forceinline__ float bf2f(ushort s) {
  return __uint_as_float(((uint)s) << 16);
}

// ======================= bucket histogram =======================
__global__ __launch_bounds__(256) void k_bhist(const int* __restrict__ dst, int E,
                                               int NB, int* __restrict__ gbhist) {
  __shared__ int lh[512];
  int t = threadIdx.x;
  lh[t] = 0;
  lh[t + 256] = 0;
  __syncthreads();
  for (int i = blockIdx.x * 256 + t; i < E; i += gridDim.x * 256)
    atomicAdd(&lh[dst[i] >> NBSHIFT], 1);
  __syncthreads();
  for (int b = t; b < NB; b += 256) {
    int c = lh[b];
    if (c) atomicAdd(&gbhist[b], c);
  }
}

// exclusive scan of gbhist[NB] -> bbase, bcursor (NB <= 512), single block
__global__ __launch_bounds__(512) void k_bscan(const int* __restrict__ gbhist, int NB,
                                               int* __restrict__ bbase,
                                               int* __restrict__ bcursor) {
  __shared__ int sb[512];
  int t = threadIdx.x;
  int v = (t < NB) ? gbhist[t] : 0;
  sb[t] = v;
  __syncthreads();
  for (int off = 1; off < 512; off <<= 1) {
    int add = (t >= off) ? sb[t - off] : 0;
    __syncthreads();
    sb[t] += add;
    __syncthreads();
  }
  if (t < NB) {
    int e = sb[t] - v;
    bbase[t] = e;
    bcursor[t] = e;
  }
}

// ======================= partition into bucket regions =======================
__global__ __launch_bounds__(256) void k_part(const int* __restrict__ src,
                                              const int* __restrict__ dst, int E,
                                              int NB, int* __restrict__ bcursor,
                                              int2* __restrict__ pairs) {
  __shared__ int lh[512];
  __shared__ int lcur[512];
  int t = threadIdx.x;
  lh[t] = 0;
  lh[t + 256] = 0;
  __syncthreads();
  int e0 = blockIdx.x * 8192;
  int e1 = min(E, e0 + 8192);
  for (int i = e0 + t; i < e1; i += 256) atomicAdd(&lh[dst[i] >> NBSHIFT], 1);
  __syncthreads();
  for (int b = t; b < NB; b += 256) {
    int c = lh[b];
    lcur[b] = c ? atomicAdd(&bcursor[b], c) : 0;
  }
  __syncthreads();
  for (int i = e0 + t; i < e1; i += 256) {
    int d = dst[i];
    int pos = atomicAdd(&lcur[d >> NBSHIFT], 1);
    pairs[pos] = make_int2(src[i], d);
  }
}

// ======================= per-bucket CSR + deg + dinv =======================
__global__ __launch_bounds__(256) void k_csr(const int2* __restrict__ pairs,
                                             const int* __restrict__ gbhist,
                                             const int* __restrict__ bbase, int n,
                                             int* __restrict__ degi,
                                             float* __restrict__ dinv,
                                             int* __restrict__ rowptr,
                                             int* __restrict__ srcs) {
  __shared__ int nh[256];
  __shared__ int ncur[256];
  int t = threadIdx.x;
  int b = blockIdx.x;
  int base = bbase[b];
  int cnt = gbhist[b];
  nh[t] = 0;
  __syncthreads();
  for (int i = t; i < cnt; i += 256) atomicAdd(&nh[pairs[base + i].y & 255], 1);
  __syncthreads();
  int node = (b << NBSHIFT) + t;
  int v = nh[t];
  if (node < n) {
    degi[node] = v;
    dinv[node] = rsqrtf((float)v + 1.0f);
  }
  __syncthreads();
  for (int off = 1; off < 256; off <<= 1) {
    int add = (t >= off) ? nh[t - off] : 0;
    __syncthreads();
    nh[t] += add;
    __syncthreads();
  }
  int excl = nh[t] - v;
  if (node < n) rowptr[node] = base + excl;
  ncur[t] = base + excl;
  __syncthreads();
  for (int i = t; i < cnt; i += 256) {
    int2 p = pairs[base + i];
    int pos = atomicAdd(&ncur[p.y & 255], 1);
    srcs[pos] = p.x;
  }
}

// ======================= GEMM1: h1(bf16) = x @ W1 =======================
__global__ __launch_bounds__(256) void k_gemm1(const float* __restrict__ x,
                                               const float* __restrict__ W,
                                               ushort* __restrict__ h, int n) {
  __shared__ float xs[64][128];
  __shared__ float Ws[128][64];
  const int t = threadIdx.x;
  const int base = blockIdx.x * 64;

  for (int i = t; i < 128 * 64; i += 256) Ws[i >> 6][i & 63] = W[i];
  for (int i = t; i < 64 * 128; i += 256) {
    int r = i >> 7, k = i & 127;
    float v = (base + r < n) ? x[(size_t)(base + r) * DIM_IN + k] : 0.0f;
    xs[r][k ^ ((r & 3) << 2)] = v;
  }
  __syncthreads();

  const int c0 = (t & 15) * 4;
  const int r0 = (t >> 4) * 4;
  float acc[4][4] = {};
  for (int kb = 0; kb < 128; kb += 4) {
    float xv[4][4];
    float wv[4][4];
#pragma unroll
    for (int i = 0; i < 4; ++i)
      *(float4*)xv[i] = *(const float4*)&xs[r0 + i][kb ^ (i << 2)];
#pragma unroll
    for (int kk = 0; kk < 4; ++kk)
      *(float4*)wv[kk] = *(const float4*)&Ws[kb + kk][c0];
#pragma unroll
    for (int kk = 0; kk < 4; ++kk)
#pragma unroll
      for (int i = 0; i < 4; ++i)
#pragma unroll
        for (int j = 0; j < 4; ++j)
          acc[i][j] = fmaf(xv[i][kk], wv[kk][j], acc[i][j]);
  }

#pragma unroll
  for (int i = 0; i < 4; ++i) {
    int r = base + r0 + i;
    if (r < n) {
      ushort4 o;
      o.x = f2bf(acc[i][0]);
      o.y = f2bf(acc[i][1]);
      o.z = f2bf(acc[i][2]);
      o.w = f2bf(acc[i][3]);
      *(ushort4*)&h[(size_t)r * DIM_H + c0] = o;
    }
  }
}

// ======================= GEMM2: h2(bf16) = relu(agg1) @ W2 =======================
__global__ __launch_bounds__(256) void k_gemm2(const float* __restrict__ a,
                                               const float* __restrict__ W,
                                               ushort* __restrict__ h2, int n) {
  __shared__ float Ws[64][16];
  const int t = threadIdx.x;
  for (int i = t; i < 64 * 16; i += 256) Ws[i >> 4][i & 15] = W[i];
  __syncthreads();
  int r = blockIdx.x * 256 + t;
  if (r >= n) return;
  const float4* ap = (const float4*)(a + (size_t)r * DIM_H);
  float acc[16] = {};
  for (int k4 = 0; k4 < 16; ++k4) {
    float4 v = ap[k4];
    float vv[4] = {fmaxf(v.x, 0.f), fmaxf(v.y, 0.f), fmaxf(v.z, 0.f),
                   fmaxf(v.w, 0.f)};
#pragma unroll
    for (int kk = 0; kk < 4; ++kk) {
      int k = k4 * 4 + kk;
#pragma unroll
      for (int j = 0; j < 16; ++j) acc[j] = fmaf(vv[kk], Ws[k][j], acc[j]);
    }
  }
  ushort4* hp = (ushort4*)(h2 + (size_t)r * DIM_OUT);
#pragma unroll
  for (int q = 0; q < 4; ++q) {
    ushort4 o;
    o.x = f2bf(acc[q * 4 + 0]);
    o.y = f2bf(acc[q * 4 + 1]);
    o.z = f2bf(acc[q * 4 + 2]);
    o.w = f2bf(acc[q * 4 + 3]);
    hp[q] = o;
  }
}

// ======================= gather aggregation =======================

// layer 1: one 64-lane wave per node; lane = column. h is bf16.
__global__ __launch_bounds__(256) void k_gather64(const ushort* __restrict__ h,
                                                  const int* __restrict__ srcs,
                                                  const int* __restrict__ rowptr,
                                                  const int* __restrict__ deg,
                                                  const float* __restrict__ dinv,
                                                  const float* __restrict__ b,
                                                  float* __restrict__ out, int n) {
  int node = blockIdx.x * 4 + (threadIdx.x >> 6);
  int lane = threadIdx.x & 63;
  if (node >= n) return;
  int start = rowptr[node];
  int cnt = deg[node];
  float dd = dinv[node];
  float acc = bf2f(h[(size_t)node * DIM_H + lane]) * dd * dd + b[lane];
  for (int j0 = 0; j0 < cnt; j0 += 64) {
    int rem = cnt - j0;
    if (rem > 64) rem = 64;
    int s_l = (lane < rem) ? srcs[start + j0 + lane] : 0;
    float w_l = dinv[s_l] * dd;
    int j = 0;
    for (; j + 4 <= rem; j += 4) {
      int s0 = __shfl(s_l, j), s1 = __shfl(s_l, j + 1);
      int s2 = __shfl(s_l, j + 2), s3 = __shfl(s_l, j + 3);
      float w0 = __shfl(w_l, j), w1 = __shfl(w_l, j + 1);
      float w2 = __shfl(w_l, j + 2), w3 = __shfl(w_l, j + 3);
      float v0 = bf2f(h[(size_t)s0 * DIM_H + lane]);
      float v1 = bf2f(h[(size_t)s1 * DIM_H + lane]);
      float v2 = bf2f(h[(size_t)s2 * DIM_H + lane]);
      float v3 = bf2f(h[(size_t)s3 * DIM_H + lane]);
      acc = fmaf(v0, w0, acc);
      acc = fmaf(v1, w1, acc);
      acc = fmaf(v2, w2, acc);
      acc = fmaf(v3, w3, acc);
    }
    for (; j < rem; ++j) {
      int s = __shfl(s_l, j);
      float w = __shfl(w_l, j);
      acc = fmaf(bf2f(h[(size_t)s * DIM_H + lane]), w, acc);
    }
  }
  out[(size_t)node * DIM_H + lane] = acc;
}

// layer 2: 16-lane group per node; fused self+bias+log_softmax. h is bf16.
__global__ __launch_bounds__(256) void k_gather16(const ushort* __restrict__ h,
                                                  const int* __restrict__ srcs,
                                                  const int* __restrict__ rowptr,
                                                  const int* __restrict__ deg,
                                                  const float* __restrict__ dinv,
                                                  const float* __restrict__ b,
                                                  float* __restrict__ out, int n) {
  int node = blockIdx.x * 16 + (threadIdx.x >> 4);
  int lane = threadIdx.x & 15;
  int gbase = (threadIdx.x & 63) & 48;
  if (node >= n) return;
  int start = rowptr[node];
  int cnt = deg[node];
  float dd = dinv[node];
  float acc = bf2f(h[(size_t)node * DIM_OUT + lane]) * dd * dd + b[lane];
  for (int j0 = 0; j0 < cnt; j0 += 16) {
    int rem = cnt - j0;
    if (rem > 16) rem = 16;
    int s_l = (lane < rem) ? srcs[start + j0 + lane] : 0;
    float w_l = dinv[s_l] * dd;
    int j = 0;
    for (; j + 4 <= rem; j += 4) {
      int s0 = __shfl(s_l, gbase + j), s1 = __shfl(s_l, gbase + j + 1);
      int s2 = __shfl(s_l, gbase + j + 2), s3 = __shfl(s_l, gbase + j + 3);
      float w0 = __shfl(w_l, gbase + j), w1 = __shfl(w_l, gbase + j + 1);
      float w2 = __shfl(w_l, gbase + j + 2), w3 = __shfl(w_l, gbase + j + 3);
      float v0 = bf2f(h[(size_t)s0 * DIM_OUT + lane]);
      float v1 = bf2f(h[(size_t)s1 * DIM_OUT + lane]);
      float v2 = bf2f(h[(size_t)s2 * DIM_OUT + lane]);
      float v3 = bf2f(h[(size_t)s3 * DIM_OUT + lane]);
      acc = fmaf(v0, w0, acc);
      acc = fmaf(v1, w1, acc);
      acc = fmaf(v2, w2, acc);
      acc = fmaf(v3, w3, acc);
    }
    for (; j < rem; ++j) {
      int s = __shfl(s_l, gbase + j);
      float w = __shfl(w_l, gbase + j);
      acc = fmaf(bf2f(h[(size_t)s * DIM_OUT + lane]), w, acc);
    }
  }
  float m = acc;
#pragma unroll
  for (int off = 1; off < 16; off <<= 1) m = fmaxf(m, __shfl_xor(m, off));
  float e = expf(acc - m);
  float ssum = e;
#pragma unroll
  for (int off = 1; off < 16; off <<= 1) ssum += __shfl_xor(ssum, off);
  out[(size_t)node * DIM_OUT + lane] = acc - m - logf(ssum);
}

// ======================= launch =======================

extern "C" void kernel_launch(void* const* d_in, const int* in_sizes, int n_in,
                              void* d_out, int out_size, void* d_ws, size_t ws_size,
                              hipStream_t stream) {
  const float* x  = (const float*)d_in[0];
  const int*   ei = (const int*)d_in[1];
  const float* W1 = (const float*)d_in[2];
  const float* b1 = (const float*)d_in[3];
  const float* W2 = (const float*)d_in[4];
  const float* b2 = (const float*)d_in[5];
  float* out = (float*)d_out;

  const int n = in_sizes[0] / DIM_IN;  // 100000
  const int E = in_sizes[1] / 2;       // 1600000
  const int* srcv = ei;
  const int* dstv = ei + E;
  const int NB = (n + 255) >> NBSHIFT;  // 391

  char* wsb = (char*)d_ws;
  int* degi    = (int*)wsb;   wsb += (size_t)n * 4;
  int* rowptr  = (int*)wsb;   wsb += (size_t)n * 4;
  float* dinv  = (float*)wsb; wsb += (size_t)n * 4;
  int* gbhist  = (int*)wsb;   wsb += 512 * 4;
  int* bbase   = (int*)wsb;   wsb += 512 * 4;
  int* bcursor = (int*)wsb;   wsb += 512 * 4;
  int* srcs    = (int*)wsb;   wsb += (size_t)E * 4;
  ushort* h1   = (ushort*)wsb; wsb += (size_t)n * DIM_H * 2;
  float* agg1  = (float*)wsb;  wsb += (size_t)n * DIM_H * 4;
  ushort* h2   = (ushort*)wsb; wsb += (size_t)n * DIM_OUT * 2;
  // pairs (E int2 = 12.8 MB) aliases agg1 (25.6 MB): dead before k_gather64 writes
  int2* pairs = (int2*)agg1;

  // ---- CSR build ----
  hipMemsetAsync(gbhist, 0, 512 * 4, stream);
  k_bhist<<<256, 256, 0, stream>>>(dstv, E, NB, gbhist);
  k_bscan<<<1, 512, 0, stream>>>(gbhist, NB, bbase, bcursor);
  k_part<<<(E + 8191) / 8192, 256, 0, stream>>>(srcv, dstv, E, NB, bcursor, pairs);
  k_csr<<<NB, 256, 0, stream>>>(pairs, gbhist, bbase, n, degi, dinv, rowptr, srcs);

  // ---- layer 1 ----
  k_gemm1<<<(n + 63) / 64, 256, 0, stream>>>(x, W1, h1, n);
  k_gather64<<<(n + 3) / 4, 256, 0, stream>>>(h1, srcs, rowptr, degi, dinv, b1,
                                              agg1, n);

  // ---- layer 2 ----
  k_gemm2<<<(n + 255) / 256, 256, 0, stream>>>(agg1, W2, h2, n);
  k_gather16<<<(n + 15) / 16, 256, 0, stream>>>(h2, srcs, rowptr, degi, dinv, b2,
                                                out, n);
}

// Round 5
// 176.524 us; speedup vs baseline: 3.4163x; 1.2705x over previous
//
#include <hip/hip_runtime.h>
#include <math.h>

#define DIM_IN 128
#define DIM_H 64
#define DIM_OUT 16
#define NBSHIFT 8  // 256 nodes per bucket

typedef __attribute__((ext_vector_type(8))) short bf16x8;
typedef __attribute__((ext_vector_type(4))) float f32x4;

__device__ __forceinline__ ushort f2bf(float f) {
  uint u = __float_as_uint(f);
  return (ushort)((u + 0x7FFF + ((u >> 16) & 1)) >> 16);
}
__device__ __forceinline__ float bf2f(ushort s) {
  return __uint_as_float(((uint)s) << 16);
}
__device__ __forceinline__ uint cvtpk(float lo, float hi) {
  uint r;
  asm("v_cvt_pk_bf16_f32 %0, %1, %2" : "=v"(r) : "v"(lo), "v"(hi));
  return r;
}

// ======================= bucket histogram =======================
__global__ __launch_bounds__(256) void k_bhist(const int* __restrict__ dst, int E,
                                               int NB, int* __restrict__ gbhist) {
  __shared__ int lh[512];
  int t = threadIdx.x;
  lh[t] = 0;
  lh[t + 256] = 0;
  __syncthreads();
  for (int i = blockIdx.x * 256 + t; i < E; i += gridDim.x * 256)
    atomicAdd(&lh[dst[i] >> NBSHIFT], 1);
  __syncthreads();
  for (int b = t; b < NB; b += 256) {
    int c = lh[b];
    if (c) atomicAdd(&gbhist[b], c);
  }
}

// exclusive scan of gbhist[NB] -> bbase, bcursor (NB <= 512), single block
__global__ __launch_bounds__(512) void k_bscan(const int* __restrict__ gbhist, int NB,
                                               int* __restrict__ bbase,
                                               int* __restrict__ bcursor) {
  __shared__ int sb[512];
  int t = threadIdx.x;
  int v = (t < NB) ? gbhist[t] : 0;
  sb[t] = v;
  __syncthreads();
  for (int off = 1; off < 512; off <<= 1) {
    int add = (t >= off) ? sb[t - off] : 0;
    __syncthreads();
    sb[t] += add;
    __syncthreads();
  }
  if (t < NB) {
    int e = sb[t] - v;
    bbase[t] = e;
    bcursor[t] = e;
  }
}

// ======================= partition into bucket regions =======================
__global__ __launch_bounds__(256) void k_part(const int* __restrict__ src,
                                              const int* __restrict__ dst, int E,
                                              int NB, int* __restrict__ bcursor,
                                              int2* __restrict__ pairs) {
  __shared__ int lh[512];
  __shared__ int lcur[512];
  int t = threadIdx.x;
  lh[t] = 0;
  lh[t + 256] = 0;
  __syncthreads();
  int e0 = blockIdx.x * 8192;
  int e1 = min(E, e0 + 8192);
  for (int i = e0 + t; i < e1; i += 256) atomicAdd(&lh[dst[i] >> NBSHIFT], 1);
  __syncthreads();
  for (int b = t; b < NB; b += 256) {
    int c = lh[b];
    lcur[b] = c ? atomicAdd(&bcursor[b], c) : 0;
  }
  __syncthreads();
  for (int i = e0 + t; i < e1; i += 256) {
    int d = dst[i];
    int pos = atomicAdd(&lcur[d >> NBSHIFT], 1);
    pairs[pos] = make_int2(src[i], d);
  }
}

// ======================= per-bucket CSR + deg + dinv =======================
__global__ __launch_bounds__(256) void k_csr(const int2* __restrict__ pairs,
                                             const int* __restrict__ gbhist,
                                             const int* __restrict__ bbase, int n,
                                             int* __restrict__ degi,
                                             float* __restrict__ dinv,
                                             int* __restrict__ rowptr,
                                             int* __restrict__ srcs) {
  __shared__ int nh[256];
  __shared__ int ncur[256];
  int t = threadIdx.x;
  int b = blockIdx.x;
  int base = bbase[b];
  int cnt = gbhist[b];
  nh[t] = 0;
  __syncthreads();
  for (int i = t; i < cnt; i += 256) atomicAdd(&nh[pairs[base + i].y & 255], 1);
  __syncthreads();
  int node = (b << NBSHIFT) + t;
  int v = nh[t];
  if (node < n) {
    degi[node] = v;
    dinv[node] = rsqrtf((float)v + 1.0f);
  }
  __syncthreads();
  for (int off = 1; off < 256; off <<= 1) {
    int add = (t >= off) ? nh[t - off] : 0;
    __syncthreads();
    nh[t] += add;
    __syncthreads();
  }
  int excl = nh[t] - v;
  if (node < n) rowptr[node] = base + excl;
  ncur[t] = base + excl;
  __syncthreads();
  for (int i = t; i < cnt; i += 256) {
    int2 p = pairs[base + i];
    int pos = atomicAdd(&ncur[p.y & 255], 1);
    srcs[pos] = p.x;
  }
}

// ======================= GEMM1 (MFMA bf16): h1 = x @ W1 =======================
// One wave owns a 16-row x 64-col tile: 4 N-tiles of 16x16x32 MFMA, K=128 in 4
// chunks. A loaded straight from global x (f32 -> cvt_pk bf16), B (all of W1)
// held in 64 VGPRs per wave. No LDS.
__global__ __launch_bounds__(256, 4) void k_gemm1m(const float* __restrict__ x,
                                                   const float* __restrict__ W,
                                                   ushort* __restrict__ h, int n,
                                                   int nTiles) {
  const int t = threadIdx.x;
  const int lane = t & 63;
  const int wid = blockIdx.x * 4 + (t >> 6);
  const int nW = gridDim.x * 4;
  const int cc = lane & 15;        // A row offset / B,D col offset
  const int kb = (lane >> 4) * 8;  // k-octet within 32-chunk

  // B fragments: bfrag[kc][nt] holds W[kc*32+kb .. +7][nt*16+cc] as bf16x8
  bf16x8 bfrag[4][4];
#pragma unroll
  for (int kc = 0; kc < 4; ++kc)
#pragma unroll
    for (int nt = 0; nt < 4; ++nt) {
      union { bf16x8 v; uint u[4]; } fb;
#pragma unroll
      for (int j = 0; j < 4; ++j) {
        float lo = W[(size_t)(kc * 32 + kb + 2 * j) * DIM_H + nt * 16 + cc];
        float hi = W[(size_t)(kc * 32 + kb + 2 * j + 1) * DIM_H + nt * 16 + cc];
        fb.u[j] = cvtpk(lo, hi);
      }
      bfrag[kc][nt] = fb.v;
    }

  for (int tile = wid; tile < nTiles; tile += nW) {
    int row0 = tile * 16;
    int ra = row0 + cc;
    if (ra > n - 1) ra = n - 1;  // clamp loads; stores are masked
    const float* xp = x + (size_t)ra * DIM_IN;
    f32x4 acc[4] = {{0.f, 0.f, 0.f, 0.f},
                    {0.f, 0.f, 0.f, 0.f},
                    {0.f, 0.f, 0.f, 0.f},
                    {0.f, 0.f, 0.f, 0.f}};
#pragma unroll
    for (int kc = 0; kc < 4; ++kc) {
      float4 a0 = *(const float4*)(xp + kc * 32 + kb);
      float4 a1 = *(const float4*)(xp + kc * 32 + kb + 4);
      union { bf16x8 v; uint u[4]; } fa;
      fa.u[0] = cvtpk(a0.x, a0.y);
      fa.u[1] = cvtpk(a0.z, a0.w);
      fa.u[2] = cvtpk(a1.x, a1.y);
      fa.u[3] = cvtpk(a1.z, a1.w);
#pragma unroll
      for (int nt = 0; nt < 4; ++nt)
        acc[nt] = __builtin_amdgcn_mfma_f32_16x16x32_bf16(fa.v, bfrag[kc][nt],
                                                          acc[nt], 0, 0, 0);
    }
    int rbase = row0 + (lane >> 4) * 4;
#pragma unroll
    for (int nt = 0; nt < 4; ++nt) {
      int col = nt * 16 + cc;
#pragma unroll
      for (int j = 0; j < 4; ++j) {
        int r = rbase + j;
        if (r < n) h[(size_t)r * DIM_H + col] = f2bf(acc[nt][j]);
      }
    }
  }
}

// ======================= GEMM2: h2(bf16) = relu(agg1) @ W2 =======================
__global__ __launch_bounds__(256) void k_gemm2(const float* __restrict__ a,
                                               const float* __restrict__ W,
                                               ushort* __restrict__ h2, int n) {
  __shared__ float Ws[64][16];
  const int t = threadIdx.x;
  for (int i = t; i < 64 * 16; i += 256) Ws[i >> 4][i & 15] = W[i];
  __syncthreads();
  int r = blockIdx.x * 256 + t;
  if (r >= n) return;
  const float4* ap = (const float4*)(a + (size_t)r * DIM_H);
  float acc[16] = {};
  for (int k4 = 0; k4 < 16; ++k4) {
    float4 v = ap[k4];
    float vv[4] = {fmaxf(v.x, 0.f), fmaxf(v.y, 0.f), fmaxf(v.z, 0.f),
                   fmaxf(v.w, 0.f)};
#pragma unroll
    for (int kk = 0; kk < 4; ++kk) {
      int k = k4 * 4 + kk;
#pragma unroll
      for (int j = 0; j < 16; ++j) acc[j] = fmaf(vv[kk], Ws[k][j], acc[j]);
    }
  }
  ushort4* hp = (ushort4*)(h2 + (size_t)r * DIM_OUT);
#pragma unroll
  for (int q = 0; q < 4; ++q) {
    ushort4 o;
    o.x = f2bf(acc[q * 4 + 0]);
    o.y = f2bf(acc[q * 4 + 1]);
    o.z = f2bf(acc[q * 4 + 2]);
    o.w = f2bf(acc[q * 4 + 3]);
    hp[q] = o;
  }
}

// ======================= gather aggregation =======================

// layer 1: one 64-lane wave per node; lane = column. h is bf16.
__global__ __launch_bounds__(256) void k_gather64(const ushort* __restrict__ h,
                                                  const int* __restrict__ srcs,
                                                  const int* __restrict__ rowptr,
                                                  const int* __restrict__ deg,
                                                  const float* __restrict__ dinv,
                                                  const float* __restrict__ b,
                                                  float* __restrict__ out, int n) {
  int node = blockIdx.x * 4 + (threadIdx.x >> 6);
  int lane = threadIdx.x & 63;
  if (node >= n) return;
  int start = rowptr[node];
  int cnt = deg[node];
  float dd = dinv[node];
  float acc = bf2f(h[(size_t)node * DIM_H + lane]) * dd * dd + b[lane];
  for (int j0 = 0; j0 < cnt; j0 += 64) {
    int rem = cnt - j0;
    if (rem > 64) rem = 64;
    int s_l = (lane < rem) ? srcs[start + j0 + lane] : 0;
    float w_l = dinv[s_l] * dd;
    int j = 0;
    for (; j + 4 <= rem; j += 4) {
      int s0 = __shfl(s_l, j), s1 = __shfl(s_l, j + 1);
      int s2 = __shfl(s_l, j + 2), s3 = __shfl(s_l, j + 3);
      float w0 = __shfl(w_l, j), w1 = __shfl(w_l, j + 1);
      float w2 = __shfl(w_l, j + 2), w3 = __shfl(w_l, j + 3);
      float v0 = bf2f(h[(size_t)s0 * DIM_H + lane]);
      float v1 = bf2f(h[(size_t)s1 * DIM_H + lane]);
      float v2 = bf2f(h[(size_t)s2 * DIM_H + lane]);
      float v3 = bf2f(h[(size_t)s3 * DIM_H + lane]);
      acc = fmaf(v0, w0, acc);
      acc = fmaf(v1, w1, acc);
      acc = fmaf(v2, w2, acc);
      acc = fmaf(v3, w3, acc);
    }
    for (; j < rem; ++j) {
      int s = __shfl(s_l, j);
      float w = __shfl(w_l, j);
      acc = fmaf(bf2f(h[(size_t)s * DIM_H + lane]), w, acc);
    }
  }
  out[(size_t)node * DIM_H + lane] = acc;
}

// layer 2: 16-lane group per node; fused self+bias+log_softmax. h is bf16.
__global__ __launch_bounds__(256) void k_gather16(const ushort* __restrict__ h,
                                                  const int* __restrict__ srcs,
                                                  const int* __restrict__ rowptr,
                                                  const int* __restrict__ deg,
                                                  const float* __restrict__ dinv,
                                                  const float* __restrict__ b,
                                                  float* __restrict__ out, int n) {
  int node = blockIdx.x * 16 + (threadIdx.x >> 4);
  int lane = threadIdx.x & 15;
  int gbase = (threadIdx.x & 63) & 48;
  if (node >= n) return;
  int start = rowptr[node];
  int cnt = deg[node];
  float dd = dinv[node];
  float acc = bf2f(h[(size_t)node * DIM_OUT + lane]) * dd * dd + b[lane];
  for (int j0 = 0; j0 < cnt; j0 += 16) {
    int rem = cnt - j0;
    if (rem > 16) rem = 16;
    int s_l = (lane < rem) ? srcs[start + j0 + lane] : 0;
    float w_l = dinv[s_l] * dd;
    int j = 0;
    for (; j + 4 <= rem; j += 4) {
      int s0 = __shfl(s_l, gbase + j), s1 = __shfl(s_l, gbase + j + 1);
      int s2 = __shfl(s_l, gbase + j + 2), s3 = __shfl(s_l, gbase + j + 3);
      float w0 = __shfl(w_l, gbase + j), w1 = __shfl(w_l, gbase + j + 1);
      float w2 = __shfl(w_l, gbase + j + 2), w3 = __shfl(w_l, gbase + j + 3);
      float v0 = bf2f(h[(size_t)s0 * DIM_OUT + lane]);
      float v1 = bf2f(h[(size_t)s1 * DIM_OUT + lane]);
      float v2 = bf2f(h[(size_t)s2 * DIM_OUT + lane]);
      float v3 = bf2f(h[(size_t)s3 * DIM_OUT + lane]);
      acc = fmaf(v0, w0, acc);
      acc = fmaf(v1, w1, acc);
      acc = fmaf(v2, w2, acc);
      acc = fmaf(v3, w3, acc);
    }
    for (; j < rem; ++j) {
      int s = __shfl(s_l, gbase + j);
      float w = __shfl(w_l, gbase + j);
      acc = fmaf(bf2f(h[(size_t)s * DIM_OUT + lane]), w, acc);
    }
  }
  float m = acc;
#pragma unroll
  for (int off = 1; off < 16; off <<= 1) m = fmaxf(m, __shfl_xor(m, off));
  float e = expf(acc - m);
  float ssum = e;
#pragma unroll
  for (int off = 1; off < 16; off <<= 1) ssum += __shfl_xor(ssum, off);
  out[(size_t)node * DIM_OUT + lane] = acc - m - logf(ssum);
}

// ======================= launch =======================

extern "C" void kernel_launch(void* const* d_in, const int* in_sizes, int n_in,
                              void* d_out, int out_size, void* d_ws, size_t ws_size,
                              hipStream_t stream) {
  const float* x  = (const float*)d_in[0];
  const int*   ei = (const int*)d_in[1];
  const float* W1 = (const float*)d_in[2];
  const float* b1 = (const float*)d_in[3];
  const float* W2 = (const float*)d_in[4];
  const float* b2 = (const float*)d_in[5];
  float* out = (float*)d_out;

  const int n = in_sizes[0] / DIM_IN;  // 100000
  const int E = in_sizes[1] / 2;       // 1600000
  const int* srcv = ei;
  const int* dstv = ei + E;
  const int NB = (n + 255) >> NBSHIFT;  // 391

  char* wsb = (char*)d_ws;
  int* degi    = (int*)wsb;   wsb += (size_t)n * 4;
  int* rowptr  = (int*)wsb;   wsb += (size_t)n * 4;
  float* dinv  = (float*)wsb; wsb += (size_t)n * 4;
  int* gbhist  = (int*)wsb;   wsb += 512 * 4;
  int* bbase   = (int*)wsb;   wsb += 512 * 4;
  int* bcursor = (int*)wsb;   wsb += 512 * 4;
  int* srcs    = (int*)wsb;   wsb += (size_t)E * 4;
  ushort* h1   = (ushort*)wsb; wsb += (size_t)n * DIM_H * 2;
  float* agg1  = (float*)wsb;  wsb += (size_t)n * DIM_H * 4;
  ushort* h2   = (ushort*)wsb; wsb += (size_t)n * DIM_OUT * 2;
  // pairs (E int2 = 12.8 MB) aliases agg1 (25.6 MB): dead before k_gather64 writes
  int2* pairs = (int2*)agg1;

  // ---- CSR build ----
  hipMemsetAsync(gbhist, 0, 512 * 4, stream);
  k_bhist<<<256, 256, 0, stream>>>(dstv, E, NB, gbhist);
  k_bscan<<<1, 512, 0, stream>>>(gbhist, NB, bbase, bcursor);
  k_part<<<(E + 8191) / 8192, 256, 0, stream>>>(srcv, dstv, E, NB, bcursor, pairs);
  k_csr<<<NB, 256, 0, stream>>>(pairs, gbhist, bbase, n, degi, dinv, rowptr, srcs);

  // ---- layer 1 ----
  k_gemm1m<<<512, 256, 0, stream>>>(x, W1, h1, n, (n + 15) / 16);
  k_gather64<<<(n + 3) / 4, 256, 0, stream>>>(h1, srcs, rowptr, degi, dinv, b1,
                                              agg1, n);

  // ---- layer 2 ----
  k_gemm2<<<(n + 255) / 256, 256, 0, stream>>>(agg1, W2, h2, n);
  k_gather16<<<(n + 15) / 16, 256, 0, stream>>>(h2, srcs, rowptr, degi, dinv, b2,
                                                out, n);
}